// Round 1
// 320.555 us; speedup vs baseline: 1.0384x; 1.0384x over previous
//
#include <hip/hip_runtime.h>
#include <math.h>

#define MC   2048
#define DD   128
#define BB   64
#define LL   16
#define NOBJ 128
#define FDIM 512
#define NN   (MC + NOBJ)
#define TEMPC 3.0f
#define THC   0.8f
#define POSC  10.0f
#define NEGC  (-10.0f)
#define EPSC  1e-8f
#define NARG  8
#define NINF  (-3.402823466e38f)
#define NSCALE 256.0f

#define QB   4                // blocks per sample
#define PART (NN / QB)        // 544 rows per block
#define TS   512              // threads per scan block (8 waves)

typedef unsigned short ushort_t;
typedef float v2f __attribute__((ext_vector_type(2)));

// ---------- fp8 e4m3 (OCP) helpers ----------
#if defined(__has_builtin)
#if __has_builtin(__builtin_amdgcn_cvt_pk_f32_fp8)
#define HAS_HW_FP8 1
#endif
#endif

__device__ __forceinline__ float e4m3_dec1(unsigned int bv) {
    unsigned int s = (bv >> 7) & 1u, E = (bv >> 3) & 15u, M = bv & 7u;
    float v;
    if (E) v = __uint_as_float(((E + 120u) << 23) | (M << 20));
    else   v = (float)M * 0.001953125f;
    return s ? -v : v;
}
__device__ __forceinline__ v2f f8pair_sw(unsigned int w) {
    v2f r; r[0] = e4m3_dec1(w & 0xffu); r[1] = e4m3_dec1((w >> 8) & 0xffu); return r;
}
#ifdef HAS_HW_FP8
#define F8LO(u) __builtin_amdgcn_cvt_pk_f32_fp8((u), false)
#define F8HI(u) __builtin_amdgcn_cvt_pk_f32_fp8((u), true)
#else
#define F8LO(u) f8pair_sw((u) & 0xffffu)
#define F8HI(u) f8pair_sw((u) >> 16)
#endif

// software RNE encoder (prep only)
__device__ __forceinline__ unsigned int f32_to_e4m3(float x) {
    float a = fabsf(x);
    unsigned int s = (__float_as_uint(x) >> 31) << 7;
    if (a == 0.0f) return s;
    if (a >= 448.0f) return s | 0x7Eu;
    int e; float m = frexpf(a, &e);            // a = m * 2^e, m in [0.5,1)
    if (e >= -5) {                             // normal
        int mant = (int)rintf(m * 16.0f);      // 8..16
        if (mant == 16) { mant = 8; e++; if (e - 1 > 8) return s | 0x7Eu; }
        return s | ((unsigned)(e - 1 + 7) << 3) | (unsigned)(mant - 8);
    } else {                                   // subnormal: M * 2^-9
        int q = (int)rintf(a * 512.0f);
        if (q >= 8) return s | 0x08u;
        return s | (unsigned)q;
    }
}

// decode 16 fp8 bytes (one uint4) to 16 floats
#define DEC16(u, g) do { \
    v2f _p0 = F8LO((u).x), _p1 = F8HI((u).x), _p2 = F8LO((u).y), _p3 = F8HI((u).y); \
    v2f _p4 = F8LO((u).z), _p5 = F8HI((u).z), _p6 = F8LO((u).w), _p7 = F8HI((u).w); \
    g[0]=_p0[0]; g[1]=_p0[1]; g[2]=_p1[0];  g[3]=_p1[1]; \
    g[4]=_p2[0]; g[5]=_p2[1]; g[6]=_p3[0];  g[7]=_p3[1]; \
    g[8]=_p4[0]; g[9]=_p4[1]; g[10]=_p5[0]; g[11]=_p5[1]; \
    g[12]=_p6[0]; g[13]=_p6[1]; g[14]=_p7[0]; g[15]=_p7[1]; \
} while (0)

// ---------------- Kernel A: objects = scene @ W_feat + b_feat ----------------
__global__ __launch_bounds__(256) void gemm_objects(
        const float* __restrict__ scene, const float* __restrict__ W,
        const float* __restrict__ bias, float* __restrict__ obj) {
    __shared__ float sA[64][68];   // sA[k][o]
    __shared__ float sB[64][68];   // sB[k][d]
    const int b  = blockIdx.y;
    const int mt = (blockIdx.x >> 1) * 64;
    const int nt = (blockIdx.x & 1) * 64;
    const int tid = threadIdx.x;
    const int tx = tid & 15, ty = tid >> 4;
    float acc[4][4] = {{0.f,0.f,0.f,0.f},{0.f,0.f,0.f,0.f},{0.f,0.f,0.f,0.f},{0.f,0.f,0.f,0.f}};
    const float* sc = scene + (size_t)b * NOBJ * FDIM;
    for (int k0 = 0; k0 < FDIM; k0 += 64) {
        {
            const int o  = tid >> 2;
            const int ks = (tid & 3) * 16;
            const float4* src = (const float4*)(sc + (size_t)(mt + o) * FDIM + k0 + ks);
            #pragma unroll
            for (int j4 = 0; j4 < 4; j4++) {
                float4 v = src[j4];
                sA[ks + j4*4 + 0][o] = v.x;
                sA[ks + j4*4 + 1][o] = v.y;
                sA[ks + j4*4 + 2][o] = v.z;
                sA[ks + j4*4 + 3][o] = v.w;
            }
        }
        {
            const int kk = tid >> 2;
            const int dq = (tid & 3) * 16;
            const float4* src = (const float4*)(W + (size_t)(k0 + kk) * DD + nt + dq);
            float4* dst = (float4*)&sB[kk][dq];
            #pragma unroll
            for (int j4 = 0; j4 < 4; j4++) dst[j4] = src[j4];
        }
        __syncthreads();
        #pragma unroll 8
        for (int kk = 0; kk < 64; kk++) {
            float4 a4 = *(const float4*)&sA[kk][ty * 4];
            float4 b4 = *(const float4*)&sB[kk][tx * 4];
            float av[4] = {a4.x, a4.y, a4.z, a4.w};
            float bv[4] = {b4.x, b4.y, b4.z, b4.w};
            #pragma unroll
            for (int i = 0; i < 4; i++)
                #pragma unroll
                for (int j = 0; j < 4; j++)
                    acc[i][j] = fmaf(av[i], bv[j], acc[i][j]);
        }
        __syncthreads();
    }
    #pragma unroll
    for (int i = 0; i < 4; i++) {
        const int o = mt + ty * 4 + i;
        float4 r;
        r.x = acc[i][0] + bias[nt + tx*4 + 0];
        r.y = acc[i][1] + bias[nt + tx*4 + 1];
        r.z = acc[i][2] + bias[nt + tx*4 + 2];
        r.w = acc[i][3] + bias[nt + tx*4 + 3];
        *(float4*)(obj + ((size_t)b * NOBJ + o) * DD + nt + tx*4) = r;
    }
}

// -------- Kernel B: row L2 norms + NORMALIZED fp8 copies (unit rows * NSCALE) --------
// Also zeroes the per-sample barrier counters (runs before scan_exec in stream order).
__global__ __launch_bounds__(256) void norms_prep(
        const float* __restrict__ ct, const float* __restrict__ obj,
        float* __restrict__ cnorm, float* __restrict__ onorm,
        unsigned char* __restrict__ ctf8, unsigned char* __restrict__ objf8,
        unsigned int* __restrict__ ctr) {
    if (blockIdx.x == 0) {
        for (int i = threadIdx.x; i < BB * 16; i += 256) ctr[i] = 0u;
    }
    const int wid = threadIdx.x >> 6, lane = threadIdx.x & 63;
    const int r = blockIdx.x * 4 + wid;
    const int NROWS = MC + BB * NOBJ;
    if (r >= NROWS) return;
    const float* row = (r < MC) ? (ct + (size_t)r * DD) : (obj + (size_t)(r - MC) * DD);
    unsigned char* brow = (r < MC) ? (ctf8 + (size_t)r * DD) : (objf8 + (size_t)(r - MC) * DD);
    float2 xy = *(const float2*)(row + lane * 2);
    float ss = xy.x * xy.x + xy.y * xy.y;
    #pragma unroll
    for (int off = 32; off; off >>= 1) ss += __shfl_xor(ss, off, 64);
    float nrm = fmaxf(sqrtf(ss), EPSC);
    float inv = NSCALE / nrm;
    unsigned int b0 = f32_to_e4m3(xy.x * inv);
    unsigned int b1 = f32_to_e4m3(xy.y * inv);
    *(ushort_t*)(brow + lane * 2) = (ushort_t)(b0 | (b1 << 8));
    if (lane == 0) {
        if (r < MC) cnorm[r] = nrm;
        else        onorm[r - MC] = nrm;
    }
}

// -------- Kernel C: precomputed verify sigmoid tables for args 0..7 ----------
__global__ __launch_bounds__(256) void sig_table(
        const float* __restrict__ ct, const float* __restrict__ obj,
        const float* __restrict__ cnorm, const float* __restrict__ onorm,
        float* __restrict__ sigc, float* __restrict__ sigo) {
    __shared__ float cv[NARG][DD];
    __shared__ float cn[NARG];
    const int tid = threadIdx.x;
    for (int a = 0; a < NARG; a++)
        for (int i = tid; i < DD; i += 256) cv[a][i] = ct[(size_t)a * DD + i];
    if (tid < NARG) cn[tid] = fmaxf(cnorm[tid], EPSC);
    __syncthreads();
    const int sub = tid & 7, slot = tid >> 3;
    #pragma unroll
    for (int p = 0; p < 2; p++) {               // 64 rows/block, 160 blocks
        const int r = blockIdx.x * 64 + p * 32 + slot;
        const float* row = (r < MC) ? (ct + (size_t)r * DD) : (obj + (size_t)(r - MC) * DD);
        float4 r0 = *(const float4*)(row + sub * 16 + 0);
        float4 r1 = *(const float4*)(row + sub * 16 + 4);
        float4 r2 = *(const float4*)(row + sub * 16 + 8);
        float4 r3 = *(const float4*)(row + sub * 16 + 12);
        float rn = fmaxf((r < MC) ? cnorm[r] : onorm[r - MC], EPSC);
        for (int a = 0; a < NARG; a++) {
            const float* c = &cv[a][sub * 16];
            float dp = 0.f;
            dp = fmaf(r0.x, c[0], dp);  dp = fmaf(r0.y, c[1], dp);
            dp = fmaf(r0.z, c[2], dp);  dp = fmaf(r0.w, c[3], dp);
            dp = fmaf(r1.x, c[4], dp);  dp = fmaf(r1.y, c[5], dp);
            dp = fmaf(r1.z, c[6], dp);  dp = fmaf(r1.w, c[7], dp);
            dp = fmaf(r2.x, c[8], dp);  dp = fmaf(r2.y, c[9], dp);
            dp = fmaf(r2.z, c[10], dp); dp = fmaf(r2.w, c[11], dp);
            dp = fmaf(r3.x, c[12], dp); dp = fmaf(r3.y, c[13], dp);
            dp = fmaf(r3.z, c[14], dp); dp = fmaf(r3.w, c[15], dp);
            dp += __shfl_xor(dp, 1, 64);
            dp += __shfl_xor(dp, 2, 64);
            dp += __shfl_xor(dp, 4, 64);
            if (sub == 0) {
                float sim = dp / (rn * cn[a]);
                float g = 1.f / (1.f + __expf(-(sim - THC) * TEMPC));
                if (r < MC) sigc[(size_t)a * MC + r] = g;
                else {
                    int ro = r - MC, bb = ro >> 7, oo = ro & 127;
                    sigo[((size_t)bb * NARG + a) * NOBJ + oo] = g;
                }
            }
        }
    }
}

// ---------------- Kernel D: per-sample program scan, QB blocks/sample ----------------
// Node rows (pre-normalized fp8, XOR-swizzled) live in LDS. Cross-block reductions
// (gather partials / max) use a double-buffered workspace slot + one agent-scope
// atomic arrive/spin barrier per transfer/exist op.

#define GATH_ROW(row_) do { \
    const int _r = (row_); \
    uint4 _u = *(const uint4*)&nd[_r * DD + ((sub ^ (_r & 7)) << 4)]; \
    const float _a = att[_r] * nrmL[_r]; \
    float _g[16]; DEC16(_u, _g); \
    _Pragma("unroll") \
    for (int _j = 0; _j < 16; _j++) ac[_j] = fmaf(_a, _g[_j], ac[_j]); \
} while (0)

#define SIM_ROW(row_, COMB) do { \
    const int _r = (row_); \
    uint4 _u = *(const uint4*)&nd[_r * DD + ((sub ^ (_r & 7)) << 4)]; \
    float _g[16]; DEC16(_u, _g); \
    float _dp = 0.f; \
    _Pragma("unroll") \
    for (int _j = 0; _j < 16; _j++) _dp = fmaf(_g[_j], vv[_j], _dp); \
    _dp += __shfl_xor(_dp, 1, 64); \
    _dp += __shfl_xor(_dp, 2, 64); \
    _dp += __shfl_xor(_dp, 4, 64); \
    if (sub == 0) { \
        const float _sim = _dp * invden; \
        const float sg = 1.f / (1.f + __expf(-(_sim - THC) * TEMPC)); \
        COMB; \
    } \
} while (0)

#define QBARRIER() do { \
    __syncthreads(); \
    if (tid == 0) { \
        __threadfence(); \
        __hip_atomic_fetch_add(myctr, 1u, __ATOMIC_RELEASE, __HIP_MEMORY_SCOPE_AGENT); \
        const unsigned _tgt = (unsigned)(QB * epoch); \
        while (__hip_atomic_load(myctr, __ATOMIC_ACQUIRE, __HIP_MEMORY_SCOPE_AGENT) < _tgt) {} \
    } \
    __syncthreads(); \
} while (0)

__global__ __launch_bounds__(TS) void scan_exec(
        const float* __restrict__ ct, const float* __restrict__ rt,
        const int* __restrict__ program,
        const float* __restrict__ cnorm, const float* __restrict__ onorm,
        const float* __restrict__ sigc, const float* __restrict__ sigo,
        const unsigned char* __restrict__ ctf8, const unsigned char* __restrict__ objf8,
        float* __restrict__ gpart, unsigned int* __restrict__ ctr,
        float* __restrict__ out, float* __restrict__ hist) {

    const int b    = blockIdx.x & (BB - 1);   // blocks b, b+64, b+128, b+192 = one sample (same XCD)
    const int q    = blockIdx.x >> 6;         // quadrant 0..3
    const int base = q * PART;
    const int tid  = threadIdx.x;
    const int lane = tid & 63, wid = tid >> 6;
    const int rg   = tid >> 3, sub = tid & 7;

    __shared__ __align__(16) unsigned char nd[PART * DD];   // 69632 B swizzled fp8 unit rows
    __shared__ __align__(16) float att[PART];
    __shared__ __align__(16) float nrmL[PART];
    __shared__ __align__(16) float vec[DD];
    __shared__ __align__(16) float gvf[DD];
    __shared__ __align__(16) float part[8 * DD];
    __shared__ float wred[8];
    __shared__ float red2[8];
    __shared__ float s_sh;
    __shared__ int   sprog[2 * LL];

    const unsigned char* myobjf8 = objf8 + (size_t)b * NOBJ * DD;

    // ---- stage node slice into LDS (XOR swizzle j^(row&7) on 16B subtiles) ----
    for (int idx = tid; idx < PART * 8; idx += TS) {
        const int row = idx >> 3, j = idx & 7;
        const int g   = base + row;
        const unsigned char* src = (g < MC) ? (ctf8 + (size_t)g * DD)
                                            : (myobjf8 + (size_t)(g - MC) * DD);
        uint4 v = *(const uint4*)(src + j * 16);
        *(uint4*)&nd[row * DD + ((j ^ (row & 7)) << 4)] = v;
    }
    for (int i = tid; i < PART; i += TS) {
        const int g = base + i;
        att[i]  = 1.0f;
        nrmL[i] = (g < MC) ? cnorm[g] : onorm[b * NOBJ + (g - MC)];
    }
    if (tid < 2 * LL) sprog[tid] = program[b * 2 * LL + tid];
    __syncthreads();

    unsigned int epoch = 0;
    float* gpb = gpart + (size_t)b * (2 * QB * 132);
    unsigned int* myctr = ctr + b * 16;

    for (int step = 0; step < LL; step++) {
        const int op  = sprog[2 * step];
        const int arg = sprog[2 * step + 1];
        float* hrow = hist + ((size_t)b * LL + step) * NN;

        if (op == 0) {                 // null
            for (int i = tid; i < PART; i += TS) hrow[base + i] = att[i];
        } else if (op == 1) {          // sel_obj
            for (int i = tid; i < PART; i += TS) {
                const int g = base + i;
                const float nv = (g < MC) ? 0.0f : att[i];
                att[i] = nv; hrow[g] = nv;
            }
        } else if (op == 2) {          // sel_con
            for (int i = tid; i < PART; i += TS) {
                const int g = base + i;
                const float nv = (g < MC) ? att[i] : 0.0f;
                att[i] = nv; hrow[g] = nv;
            }
        } else if (op == 3 && arg < NARG) {   // verify via table
            const float* sc = sigc + (size_t)arg * MC;
            const float* so = sigo + ((size_t)b * NARG + arg) * NOBJ;
            for (int i = tid; i < PART; i += TS) {
                const int g = base + i;
                const float gg = (g < MC) ? sc[g] : so[g - MC];
                const float nv = fminf(att[i], gg);
                att[i] = nv; hrow[g] = nv;
            }
        } else if (op == 3) {          // verify fallback, arg >= NARG (never hit for this data)
            __syncthreads();
            if (tid < DD) vec[tid] = ct[(size_t)arg * DD + tid];
            __syncthreads();
            const float cn = fmaxf(cnorm[arg], EPSC);
            const float invden = 1.0f / (NSCALE * cn);
            float vv[16];
            {
                const float4 v0 = *(const float4*)&vec[sub * 16 + 0];
                const float4 v1 = *(const float4*)&vec[sub * 16 + 4];
                const float4 v2 = *(const float4*)&vec[sub * 16 + 8];
                const float4 v3 = *(const float4*)&vec[sub * 16 + 12];
                vv[0]=v0.x; vv[1]=v0.y; vv[2]=v0.z; vv[3]=v0.w;
                vv[4]=v1.x; vv[5]=v1.y; vv[6]=v1.z; vv[7]=v1.w;
                vv[8]=v2.x; vv[9]=v2.y; vv[10]=v2.z; vv[11]=v2.w;
                vv[12]=v3.x; vv[13]=v3.y; vv[14]=v3.z; vv[15]=v3.w;
            }
            #pragma unroll
            for (int p = 0; p < 8; p++) SIM_ROW(rg + p * 64, att[_r] = fminf(att[_r], sg));
            if (rg < PART - 512) SIM_ROW(rg + 512, att[_r] = fminf(att[_r], sg));
            __syncthreads();
            for (int i = tid; i < PART; i += TS) hrow[base + i] = att[i];
        } else if (op == 4) {          // choose
            for (int i = tid; i < PART; i += TS) {
                const int g = base + i;
                const float nv = (g < MC) ? ((g == arg) ? 1.0f : 0.0f) : att[i];
                att[i] = nv; hrow[g] = nv;
            }
        } else if (op == 5) {          // exist
            __syncthreads();
            float lm = NINF;
            for (int i = tid; i < PART; i += TS) lm = fmaxf(lm, att[i]);
            #pragma unroll
            for (int off = 32; off; off >>= 1) lm = fmaxf(lm, __shfl_xor(lm, off, 64));
            if (lane == 0) wred[wid] = lm;
            __syncthreads();
            epoch++;
            if (tid == 0) {
                float m = wred[0];
                #pragma unroll
                for (int w = 1; w < 8; w++) m = fmaxf(m, wred[w]);
                __hip_atomic_store(&gpb[(size_t)((epoch & 1) * QB + q) * 132 + DD], m,
                                   __ATOMIC_RELAXED, __HIP_MEMORY_SCOPE_AGENT);
            }
            QBARRIER();
            if (tid == 0) {
                float* slotR = gpb + (size_t)((epoch & 1) * QB) * 132;
                float m = NINF;
                #pragma unroll
                for (int k = 0; k < QB; k++)
                    m = fmaxf(m, __hip_atomic_load(&slotR[k * 132 + DD],
                                 __ATOMIC_RELAXED, __HIP_MEMORY_SCOPE_AGENT));
                s_sh = m;
            }
            __syncthreads();
            const float s = s_sh;
            const float yes = s * POSC, no = POSC - yes;
            for (int i = tid; i < PART; i += TS) {
                const int g = base + i;
                const float nv = (g == 0) ? yes : ((g == 1) ? no : NEGC);
                att[i] = nv; hrow[g] = nv;
            }
        } else if (op == 6) {          // transfer
            __syncthreads();
            // local max
            float lm = NINF;
            for (int i = tid; i < PART; i += TS) lm = fmaxf(lm, att[i]);
            #pragma unroll
            for (int off = 32; off; off >>= 1) lm = fmaxf(lm, __shfl_xor(lm, off, 64));
            if (lane == 0) wred[wid] = lm;
            // local gather partial over own rows (LDS-resident)
            float ac[16];
            #pragma unroll
            for (int j = 0; j < 16; j++) ac[j] = 0.f;
            #pragma unroll
            for (int p = 0; p < 8; p++) GATH_ROW(rg + p * 64);
            if (rg < PART - 512) GATH_ROW(rg + 512);
            #pragma unroll
            for (int j = 0; j < 16; j++) {
                ac[j] += __shfl_xor(ac[j], 8, 64);
                ac[j] += __shfl_xor(ac[j], 16, 64);
                ac[j] += __shfl_xor(ac[j], 32, 64);
            }
            if (lane < 8) {
                float* dst = &part[wid * DD + lane * 16];
                #pragma unroll
                for (int k = 0; k < 4; k++)
                    *(float4*)(dst + k * 4) = make_float4(ac[k*4], ac[k*4+1], ac[k*4+2], ac[k*4+3]);
            }
            __syncthreads();
            epoch++;
            {
                float* slotW = gpb + (size_t)((epoch & 1) * QB + q) * 132;
                if (tid < DD) {
                    float gsum = 0.f;
                    #pragma unroll
                    for (int w = 0; w < 8; w++) gsum += part[w * DD + tid];
                    __hip_atomic_store(&slotW[tid], gsum, __ATOMIC_RELAXED, __HIP_MEMORY_SCOPE_AGENT);
                }
                if (tid == DD) {
                    float m = wred[0];
                    #pragma unroll
                    for (int w = 1; w < 8; w++) m = fmaxf(m, wred[w]);
                    __hip_atomic_store(&slotW[DD], m, __ATOMIC_RELAXED, __HIP_MEMORY_SCOPE_AGENT);
                }
            }
            // prefetch rmat rows into regs; loads retire under the barrier wait
            const float* rm = rt + (size_t)arg * (DD * DD);
            const int half = lane >> 5, dq = (lane & 31) * 4;
            float4 rmr[8];
            #pragma unroll
            for (int j = 0; j < 8; j++) {
                const int d = wid * 16 + half * 8 + j;
                rmr[j] = *(const float4*)(rm + (size_t)d * DD + dq);
            }
            QBARRIER();
            // combine gather partials + global max
            {
                float* slotR = gpb + (size_t)((epoch & 1) * QB) * 132;
                if (tid < DD) {
                    float gsum = 0.f;
                    #pragma unroll
                    for (int k = 0; k < QB; k++)
                        gsum += __hip_atomic_load(&slotR[k * 132 + tid],
                                  __ATOMIC_RELAXED, __HIP_MEMORY_SCOPE_AGENT);
                    gvf[tid] = gsum;
                }
                if (tid == DD) {
                    float m = NINF;
                    #pragma unroll
                    for (int k = 0; k < QB; k++)
                        m = fmaxf(m, __hip_atomic_load(&slotR[k * 132 + DD],
                                     __ATOMIC_RELAXED, __HIP_MEMORY_SCOPE_AGENT));
                    s_sh = m;
                }
            }
            __syncthreads();
            // trans = gvf @ rmat (full, redundant per block, from prefetched regs)
            float qx = 0.f, qy = 0.f, qz = 0.f, qw = 0.f;
            #pragma unroll
            for (int j = 0; j < 8; j++) {
                const int d = wid * 16 + half * 8 + j;
                const float g = gvf[d];
                qx = fmaf(g, rmr[j].x, qx); qy = fmaf(g, rmr[j].y, qy);
                qz = fmaf(g, rmr[j].z, qz); qw = fmaf(g, rmr[j].w, qw);
            }
            qx += __shfl_xor(qx, 32, 64); qy += __shfl_xor(qy, 32, 64);
            qz += __shfl_xor(qz, 32, 64); qw += __shfl_xor(qw, 32, 64);
            if (lane < 32) *(float4*)&part[wid * DD + dq] = make_float4(qx, qy, qz, qw);
            __syncthreads();
            if (tid < DD) {
                float t = 0.f;
                #pragma unroll
                for (int w = 0; w < 8; w++) t += part[w * DD + tid];
                vec[tid] = t;
                float ss = t * t;
                #pragma unroll
                for (int off = 32; off; off >>= 1) ss += __shfl_xor(ss, off, 64);
                if (lane == 0) red2[wid] = ss;
            }
            __syncthreads();
            const float tn = fmaxf(sqrtf(red2[0] + red2[1]), EPSC * NSCALE);
            const float invden = 1.0f / (NSCALE * tn);
            const float s = s_sh;
            float vv[16];
            {
                const float4 v0 = *(const float4*)&vec[sub * 16 + 0];
                const float4 v1 = *(const float4*)&vec[sub * 16 + 4];
                const float4 v2 = *(const float4*)&vec[sub * 16 + 8];
                const float4 v3 = *(const float4*)&vec[sub * 16 + 12];
                vv[0]=v0.x; vv[1]=v0.y; vv[2]=v0.z; vv[3]=v0.w;
                vv[4]=v1.x; vv[5]=v1.y; vv[6]=v1.z; vv[7]=v1.w;
                vv[8]=v2.x; vv[9]=v2.y; vv[10]=v2.z; vv[11]=v2.w;
                vv[12]=v3.x; vv[13]=v3.y; vv[14]=v3.z; vv[15]=v3.w;
            }
            #pragma unroll
            for (int p = 0; p < 8; p++) SIM_ROW(rg + p * 64, att[_r] = sg * s);
            if (rg < PART - 512) SIM_ROW(rg + 512, att[_r] = sg * s);
            __syncthreads();
            for (int i = tid; i < PART; i += TS) hrow[base + i] = att[i];
        }
    }

    // ---- log_softmax over concept rows (cross-block max then sum) ----
    __syncthreads();
    const int crows = (base + PART <= MC) ? PART : (MC - base);   // 544,544,544,416
    {
        float lm = NINF;
        for (int i = tid; i < crows; i += TS) lm = fmaxf(lm, att[i]);
        #pragma unroll
        for (int off = 32; off; off >>= 1) lm = fmaxf(lm, __shfl_xor(lm, off, 64));
        if (lane == 0) wred[wid] = lm;
    }
    __syncthreads();
    epoch++;
    if (tid == 0) {
        float m = wred[0];
        #pragma unroll
        for (int w = 1; w < 8; w++) m = fmaxf(m, wred[w]);
        __hip_atomic_store(&gpb[(size_t)((epoch & 1) * QB + q) * 132 + DD], m,
                           __ATOMIC_RELAXED, __HIP_MEMORY_SCOPE_AGENT);
    }
    QBARRIER();
    if (tid == 0) {
        float* slotR = gpb + (size_t)((epoch & 1) * QB) * 132;
        float m = NINF;
        #pragma unroll
        for (int k = 0; k < QB; k++)
            m = fmaxf(m, __hip_atomic_load(&slotR[k * 132 + DD],
                         __ATOMIC_RELAXED, __HIP_MEMORY_SCOPE_AGENT));
        s_sh = m;
    }
    __syncthreads();
    const float mglob = s_sh;
    {
        float lse = 0.f;
        for (int i = tid; i < crows; i += TS) lse += expf(att[i] - mglob);
        #pragma unroll
        for (int off = 32; off; off >>= 1) lse += __shfl_xor(lse, off, 64);
        if (lane == 0) wred[wid] = lse;
    }
    __syncthreads();
    epoch++;
    if (tid == 0) {
        float se = 0.f;
        #pragma unroll
        for (int w = 0; w < 8; w++) se += wred[w];
        __hip_atomic_store(&gpb[(size_t)((epoch & 1) * QB + q) * 132 + DD], se,
                           __ATOMIC_RELAXED, __HIP_MEMORY_SCOPE_AGENT);
    }
    QBARRIER();
    if (tid == 0) {
        float* slotR = gpb + (size_t)((epoch & 1) * QB) * 132;
        float se = 0.f;
        #pragma unroll
        for (int k = 0; k < QB; k++)
            se += __hip_atomic_load(&slotR[k * 132 + DD],
                    __ATOMIC_RELAXED, __HIP_MEMORY_SCOPE_AGENT);
        s_sh = se;
    }
    __syncthreads();
    const float ls = logf(s_sh);
    for (int i = tid; i < crows; i += TS)
        out[(size_t)b * MC + base + i] = att[i] - mglob - ls;
}

extern "C" void kernel_launch(void* const* d_in, const int* in_sizes, int n_in,
                              void* d_out, int out_size, void* d_ws, size_t ws_size,
                              hipStream_t stream) {
    const float* scene = (const float*)d_in[0];
    const int*   prog  = (const int*)d_in[1];
    const float* ct    = (const float*)d_in[2];
    const float* rt    = (const float*)d_in[3];
    const float* W     = (const float*)d_in[4];
    const float* bias  = (const float*)d_in[5];

    float* out  = (float*)d_out;
    float* hist = out + (size_t)BB * MC;

    float* obj   = (float*)d_ws;                               // B*NOBJ*D f32
    float* cnorm = obj + (size_t)BB * NOBJ * DD;               // MC
    float* onorm = cnorm + MC;                                 // B*NOBJ
    float* sigc  = onorm + (size_t)BB * NOBJ;                  // NARG*MC
    float* sigo  = sigc + (size_t)NARG * MC;                   // B*NARG*NOBJ
    float* gpart = sigo + (size_t)BB * NARG * NOBJ;            // B*2*QB*132 f32
    unsigned int* ctrbuf = (unsigned int*)(gpart + (size_t)BB * 2 * QB * 132);  // B*16 u32
    unsigned char* ctf8  = (unsigned char*)(ctrbuf + BB * 16); // MC*DD bytes (normalized fp8)
    unsigned char* objf8 = ctf8 + (size_t)MC * DD;             // B*NOBJ*DD bytes

    gemm_objects<<<dim3(4, BB), 256, 0, stream>>>(scene, W, bias, obj);
    norms_prep<<<dim3((MC + BB * NOBJ) / 4), 256, 0, stream>>>(ct, obj, cnorm, onorm,
                                                               ctf8, objf8, ctrbuf);
    sig_table<<<dim3((MC + BB * NOBJ) / 64), 256, 0, stream>>>(ct, obj, cnorm, onorm, sigc, sigo);
    scan_exec<<<dim3(BB * QB), TS, 0, stream>>>(ct, rt, prog, cnorm, onorm, sigc, sigo,
                                                ctf8, objf8, gpart, ctrbuf, out, hist);
}

// Round 2
// 259.529 us; speedup vs baseline: 1.2825x; 1.2351x over previous
//
#include <hip/hip_runtime.h>
#include <math.h>

#define MC   2048
#define DD   128
#define BB   64
#define LL   16
#define NOBJ 128
#define FDIM 512
#define NN   (MC + NOBJ)
#define TEMPC 3.0f
#define THC   0.8f
#define POSC  10.0f
#define NEGC  (-10.0f)
#define EPSC  1e-8f
#define NARG  8
#define NINF  (-3.402823466e38f)
#define NSCALE 256.0f

#define QB   4                // blocks per sample
#define PART (NN / QB)        // 544 rows per block
#define TS   512              // threads per scan block (8 waves)

typedef unsigned short ushort_t;
typedef float v2f __attribute__((ext_vector_type(2)));

// ---------- fp8 e4m3 (OCP) helpers ----------
#if defined(__has_builtin)
#if __has_builtin(__builtin_amdgcn_cvt_pk_f32_fp8)
#define HAS_HW_FP8 1
#endif
#endif

__device__ __forceinline__ float e4m3_dec1(unsigned int bv) {
    unsigned int s = (bv >> 7) & 1u, E = (bv >> 3) & 15u, M = bv & 7u;
    float v;
    if (E) v = __uint_as_float(((E + 120u) << 23) | (M << 20));
    else   v = (float)M * 0.001953125f;
    return s ? -v : v;
}
__device__ __forceinline__ v2f f8pair_sw(unsigned int w) {
    v2f r; r[0] = e4m3_dec1(w & 0xffu); r[1] = e4m3_dec1((w >> 8) & 0xffu); return r;
}
#ifdef HAS_HW_FP8
#define F8LO(u) __builtin_amdgcn_cvt_pk_f32_fp8((u), false)
#define F8HI(u) __builtin_amdgcn_cvt_pk_f32_fp8((u), true)
#else
#define F8LO(u) f8pair_sw((u) & 0xffffu)
#define F8HI(u) f8pair_sw((u) >> 16)
#endif

// software RNE encoder (prep only)
__device__ __forceinline__ unsigned int f32_to_e4m3(float x) {
    float a = fabsf(x);
    unsigned int s = (__float_as_uint(x) >> 31) << 7;
    if (a == 0.0f) return s;
    if (a >= 448.0f) return s | 0x7Eu;
    int e; float m = frexpf(a, &e);            // a = m * 2^e, m in [0.5,1)
    if (e >= -5) {                             // normal
        int mant = (int)rintf(m * 16.0f);      // 8..16
        if (mant == 16) { mant = 8; e++; if (e - 1 > 8) return s | 0x7Eu; }
        return s | ((unsigned)(e - 1 + 7) << 3) | (unsigned)(mant - 8);
    } else {                                   // subnormal: M * 2^-9
        int q = (int)rintf(a * 512.0f);
        if (q >= 8) return s | 0x08u;
        return s | (unsigned)q;
    }
}

// decode 16 fp8 bytes (one uint4) to 16 floats
#define DEC16(u, g) do { \
    v2f _p0 = F8LO((u).x), _p1 = F8HI((u).x), _p2 = F8LO((u).y), _p3 = F8HI((u).y); \
    v2f _p4 = F8LO((u).z), _p5 = F8HI((u).z), _p6 = F8LO((u).w), _p7 = F8HI((u).w); \
    g[0]=_p0[0]; g[1]=_p0[1]; g[2]=_p1[0];  g[3]=_p1[1]; \
    g[4]=_p2[0]; g[5]=_p2[1]; g[6]=_p3[0];  g[7]=_p3[1]; \
    g[8]=_p4[0]; g[9]=_p4[1]; g[10]=_p5[0]; g[11]=_p5[1]; \
    g[12]=_p6[0]; g[13]=_p6[1]; g[14]=_p7[0]; g[15]=_p7[1]; \
} while (0)

// ---------------- Kernel A: objects = scene @ W_feat + b_feat ----------------
__global__ __launch_bounds__(256) void gemm_objects(
        const float* __restrict__ scene, const float* __restrict__ W,
        const float* __restrict__ bias, float* __restrict__ obj) {
    __shared__ float sA[64][68];   // sA[k][o]
    __shared__ float sB[64][68];   // sB[k][d]
    const int b  = blockIdx.y;
    const int mt = (blockIdx.x >> 1) * 64;
    const int nt = (blockIdx.x & 1) * 64;
    const int tid = threadIdx.x;
    const int tx = tid & 15, ty = tid >> 4;
    float acc[4][4] = {{0.f,0.f,0.f,0.f},{0.f,0.f,0.f,0.f},{0.f,0.f,0.f,0.f},{0.f,0.f,0.f,0.f}};
    const float* sc = scene + (size_t)b * NOBJ * FDIM;
    for (int k0 = 0; k0 < FDIM; k0 += 64) {
        {
            const int o  = tid >> 2;
            const int ks = (tid & 3) * 16;
            const float4* src = (const float4*)(sc + (size_t)(mt + o) * FDIM + k0 + ks);
            #pragma unroll
            for (int j4 = 0; j4 < 4; j4++) {
                float4 v = src[j4];
                sA[ks + j4*4 + 0][o] = v.x;
                sA[ks + j4*4 + 1][o] = v.y;
                sA[ks + j4*4 + 2][o] = v.z;
                sA[ks + j4*4 + 3][o] = v.w;
            }
        }
        {
            const int kk = tid >> 2;
            const int dq = (tid & 3) * 16;
            const float4* src = (const float4*)(W + (size_t)(k0 + kk) * DD + nt + dq);
            float4* dst = (float4*)&sB[kk][dq];
            #pragma unroll
            for (int j4 = 0; j4 < 4; j4++) dst[j4] = src[j4];
        }
        __syncthreads();
        #pragma unroll 8
        for (int kk = 0; kk < 64; kk++) {
            float4 a4 = *(const float4*)&sA[kk][ty * 4];
            float4 b4 = *(const float4*)&sB[kk][tx * 4];
            float av[4] = {a4.x, a4.y, a4.z, a4.w};
            float bv[4] = {b4.x, b4.y, b4.z, b4.w};
            #pragma unroll
            for (int i = 0; i < 4; i++)
                #pragma unroll
                for (int j = 0; j < 4; j++)
                    acc[i][j] = fmaf(av[i], bv[j], acc[i][j]);
        }
        __syncthreads();
    }
    #pragma unroll
    for (int i = 0; i < 4; i++) {
        const int o = mt + ty * 4 + i;
        float4 r;
        r.x = acc[i][0] + bias[nt + tx*4 + 0];
        r.y = acc[i][1] + bias[nt + tx*4 + 1];
        r.z = acc[i][2] + bias[nt + tx*4 + 2];
        r.w = acc[i][3] + bias[nt + tx*4 + 3];
        *(float4*)(obj + ((size_t)b * NOBJ + o) * DD + nt + tx*4) = r;
    }
}

#define NBN ((MC + BB * NOBJ) / 4)   // 2560 norm blocks

// -------- Kernel B (fused): norms + normalized fp8 copies + sig tables ------
// Blocks [0, NBN): row L2 norms + fp8 unit rows (block 0 also zeroes barrier ctrs).
// Blocks [NBN, NBN+160): verify sigmoid tables (norms computed inline).
__global__ __launch_bounds__(256) void prep_fused(
        const float* __restrict__ ct, const float* __restrict__ obj,
        float* __restrict__ cnorm, float* __restrict__ onorm,
        unsigned char* __restrict__ ctf8, unsigned char* __restrict__ objf8,
        unsigned int* __restrict__ ctr,
        float* __restrict__ sigc, float* __restrict__ sigo) {
    if (blockIdx.x < NBN) {
        if (blockIdx.x == 0) {
            for (int i = threadIdx.x; i < BB * 16; i += 256) ctr[i] = 0u;
        }
        const int wid = threadIdx.x >> 6, lane = threadIdx.x & 63;
        const int r = blockIdx.x * 4 + wid;
        const float* row = (r < MC) ? (ct + (size_t)r * DD) : (obj + (size_t)(r - MC) * DD);
        unsigned char* brow = (r < MC) ? (ctf8 + (size_t)r * DD) : (objf8 + (size_t)(r - MC) * DD);
        float2 xy = *(const float2*)(row + lane * 2);
        float ss = xy.x * xy.x + xy.y * xy.y;
        #pragma unroll
        for (int off = 32; off; off >>= 1) ss += __shfl_xor(ss, off, 64);
        float nrm = fmaxf(sqrtf(ss), EPSC);
        float inv = NSCALE / nrm;
        unsigned int b0 = f32_to_e4m3(xy.x * inv);
        unsigned int b1 = f32_to_e4m3(xy.y * inv);
        *(ushort_t*)(brow + lane * 2) = (ushort_t)(b0 | (b1 << 8));
        if (lane == 0) {
            if (r < MC) cnorm[r] = nrm;
            else        onorm[r - MC] = nrm;
        }
        return;
    }
    // ---- sig-table branch ----
    __shared__ float cv[NARG][DD];
    __shared__ float cn[NARG];
    const int tid = threadIdx.x;
    for (int a = 0; a < NARG; a++)
        for (int i = tid; i < DD; i += 256) cv[a][i] = ct[(size_t)a * DD + i];
    __syncthreads();
    if (tid < NARG) {
        float ss = 0.f;
        for (int i = 0; i < DD; i++) ss = fmaf(cv[tid][i], cv[tid][i], ss);
        cn[tid] = fmaxf(sqrtf(ss), EPSC);
    }
    __syncthreads();
    const int sub = tid & 7, slot = tid >> 3;
    #pragma unroll
    for (int p = 0; p < 2; p++) {               // 64 rows/block, 160 blocks
        const int r = (blockIdx.x - NBN) * 64 + p * 32 + slot;
        const float* row = (r < MC) ? (ct + (size_t)r * DD) : (obj + (size_t)(r - MC) * DD);
        float4 r0 = *(const float4*)(row + sub * 16 + 0);
        float4 r1 = *(const float4*)(row + sub * 16 + 4);
        float4 r2 = *(const float4*)(row + sub * 16 + 8);
        float4 r3 = *(const float4*)(row + sub * 16 + 12);
        // inline row norm
        float ssr = 0.f;
        ssr = fmaf(r0.x, r0.x, ssr); ssr = fmaf(r0.y, r0.y, ssr);
        ssr = fmaf(r0.z, r0.z, ssr); ssr = fmaf(r0.w, r0.w, ssr);
        ssr = fmaf(r1.x, r1.x, ssr); ssr = fmaf(r1.y, r1.y, ssr);
        ssr = fmaf(r1.z, r1.z, ssr); ssr = fmaf(r1.w, r1.w, ssr);
        ssr = fmaf(r2.x, r2.x, ssr); ssr = fmaf(r2.y, r2.y, ssr);
        ssr = fmaf(r2.z, r2.z, ssr); ssr = fmaf(r2.w, r2.w, ssr);
        ssr = fmaf(r3.x, r3.x, ssr); ssr = fmaf(r3.y, r3.y, ssr);
        ssr = fmaf(r3.z, r3.z, ssr); ssr = fmaf(r3.w, r3.w, ssr);
        ssr += __shfl_xor(ssr, 1, 64);
        ssr += __shfl_xor(ssr, 2, 64);
        ssr += __shfl_xor(ssr, 4, 64);
        float rn = fmaxf(sqrtf(ssr), EPSC);
        for (int a = 0; a < NARG; a++) {
            const float* c = &cv[a][sub * 16];
            float dp = 0.f;
            dp = fmaf(r0.x, c[0], dp);  dp = fmaf(r0.y, c[1], dp);
            dp = fmaf(r0.z, c[2], dp);  dp = fmaf(r0.w, c[3], dp);
            dp = fmaf(r1.x, c[4], dp);  dp = fmaf(r1.y, c[5], dp);
            dp = fmaf(r1.z, c[6], dp);  dp = fmaf(r1.w, c[7], dp);
            dp = fmaf(r2.x, c[8], dp);  dp = fmaf(r2.y, c[9], dp);
            dp = fmaf(r2.z, c[10], dp); dp = fmaf(r2.w, c[11], dp);
            dp = fmaf(r3.x, c[12], dp); dp = fmaf(r3.y, c[13], dp);
            dp = fmaf(r3.z, c[14], dp); dp = fmaf(r3.w, c[15], dp);
            dp += __shfl_xor(dp, 1, 64);
            dp += __shfl_xor(dp, 2, 64);
            dp += __shfl_xor(dp, 4, 64);
            if (sub == 0) {
                float sim = dp / (rn * cn[a]);
                float g = 1.f / (1.f + __expf(-(sim - THC) * TEMPC));
                if (r < MC) sigc[(size_t)a * MC + r] = g;
                else {
                    int ro = r - MC, bb = ro >> 7, oo = ro & 127;
                    sigo[((size_t)bb * NARG + a) * NOBJ + oo] = g;
                }
            }
        }
    }
}

// ---------------- Kernel D: per-sample program scan, QB blocks/sample ----------------
// Fence-free cross-block exchange: all data via RELAXED agent-scope atomics
// (per-access coherent at the device coherence point, no buffer_wbl2/buffer_inv).
// Ordering data->flag is provided by __syncthreads()' implicit vmcnt(0) drain.

#define GATH_ROW(row_) do { \
    const int _r = (row_); \
    uint4 _u = *(const uint4*)&nd[_r * DD + ((sub ^ (_r & 7)) << 4)]; \
    const float _a = att[_r] * nrmL[_r]; \
    float _g[16]; DEC16(_u, _g); \
    _Pragma("unroll") \
    for (int _j = 0; _j < 16; _j++) ac[_j] = fmaf(_a, _g[_j], ac[_j]); \
} while (0)

#define SIM_ROW(row_, COMB) do { \
    const int _r = (row_); \
    uint4 _u = *(const uint4*)&nd[_r * DD + ((sub ^ (_r & 7)) << 4)]; \
    float _g[16]; DEC16(_u, _g); \
    float _dp = 0.f; \
    _Pragma("unroll") \
    for (int _j = 0; _j < 16; _j++) _dp = fmaf(_g[_j], vv[_j], _dp); \
    _dp += __shfl_xor(_dp, 1, 64); \
    _dp += __shfl_xor(_dp, 2, 64); \
    _dp += __shfl_xor(_dp, 4, 64); \
    if (sub == 0) { \
        const float _sim = _dp * invden; \
        const float sg = 1.f / (1.f + __expf(-(_sim - THC) * TEMPC)); \
        COMB; \
    } \
} while (0)

#define AST(p, v) __hip_atomic_store((p), (v), __ATOMIC_RELAXED, __HIP_MEMORY_SCOPE_AGENT)
#define ALD(p)    __hip_atomic_load((p), __ATOMIC_RELAXED, __HIP_MEMORY_SCOPE_AGENT)

// Fence-free barrier: first __syncthreads drains every wave's vmcnt(0), so all
// prior sc1 (agent-relaxed) stores are complete at the coherence point before
// the relaxed flag RMW is issued.
#define QBARRIER() do { \
    __syncthreads(); \
    if (tid == 0) { \
        __hip_atomic_fetch_add(myctr, 1u, __ATOMIC_RELAXED, __HIP_MEMORY_SCOPE_AGENT); \
        const unsigned _tgt = (unsigned)(QB * epoch); \
        while (__hip_atomic_load(myctr, __ATOMIC_RELAXED, __HIP_MEMORY_SCOPE_AGENT) < _tgt) \
            __builtin_amdgcn_s_sleep(1); \
    } \
    __syncthreads(); \
} while (0)

__global__ __launch_bounds__(TS) void scan_exec(
        const float* __restrict__ ct, const float* __restrict__ rt,
        const int* __restrict__ program,
        const float* __restrict__ cnorm, const float* __restrict__ onorm,
        const float* __restrict__ sigc, const float* __restrict__ sigo,
        const unsigned char* __restrict__ ctf8, const unsigned char* __restrict__ objf8,
        float* __restrict__ gpart, unsigned int* __restrict__ ctr,
        float* __restrict__ out, float* __restrict__ hist) {

    const int b    = blockIdx.x & (BB - 1);   // blocks b, b+64, b+128, b+192 = one sample
    const int q    = blockIdx.x >> 6;         // quadrant 0..3
    const int base = q * PART;
    const int tid  = threadIdx.x;
    const int lane = tid & 63, wid = tid >> 6;
    const int rg   = tid >> 3, sub = tid & 7;

    __shared__ __align__(16) unsigned char nd[PART * DD];   // 69632 B swizzled fp8 unit rows
    __shared__ __align__(16) float att[PART];
    __shared__ __align__(16) float nrmL[PART];
    __shared__ __align__(16) float vec[DD];
    __shared__ __align__(16) float gvf[DD];
    // Oversized on purpose (only rows 0..7 used): pushes LDS past 80 KiB so the
    // scheduler places exactly 1 block/CU (256 blocks <-> 256 CUs, no CU sharing,
    // minimal quadrant skew at the barriers).
    __shared__ __align__(16) float part[14 * DD];
    __shared__ float wred[8];
    __shared__ float red2[8];
    __shared__ float s_sh;
    __shared__ float s_sh2;
    __shared__ int   sprog[2 * LL];

    const unsigned char* myobjf8 = objf8 + (size_t)b * NOBJ * DD;

    // ---- stage node slice into LDS (XOR swizzle j^(row&7) on 16B subtiles) ----
    for (int idx = tid; idx < PART * 8; idx += TS) {
        const int row = idx >> 3, j = idx & 7;
        const int g   = base + row;
        const unsigned char* src = (g < MC) ? (ctf8 + (size_t)g * DD)
                                            : (myobjf8 + (size_t)(g - MC) * DD);
        uint4 v = *(const uint4*)(src + j * 16);
        *(uint4*)&nd[row * DD + ((j ^ (row & 7)) << 4)] = v;
    }
    for (int i = tid; i < PART; i += TS) {
        const int g = base + i;
        att[i]  = 1.0f;
        nrmL[i] = (g < MC) ? cnorm[g] : onorm[b * NOBJ + (g - MC)];
    }
    if (tid < 2 * LL) sprog[tid] = program[b * 2 * LL + tid];
    __syncthreads();

    unsigned int epoch = 0;
    float* gpb = gpart + (size_t)b * (2 * QB * 132);
    unsigned int* myctr = ctr + b * 16;

    for (int step = 0; step < LL; step++) {
        const int op  = sprog[2 * step];
        const int arg = sprog[2 * step + 1];
        float* hrow = hist + ((size_t)b * LL + step) * NN;

        if (op == 0) {                 // null
            for (int i = tid; i < PART; i += TS) hrow[base + i] = att[i];
        } else if (op == 1) {          // sel_obj
            for (int i = tid; i < PART; i += TS) {
                const int g = base + i;
                const float nv = (g < MC) ? 0.0f : att[i];
                att[i] = nv; hrow[g] = nv;
            }
        } else if (op == 2) {          // sel_con
            for (int i = tid; i < PART; i += TS) {
                const int g = base + i;
                const float nv = (g < MC) ? att[i] : 0.0f;
                att[i] = nv; hrow[g] = nv;
            }
        } else if (op == 3 && arg < NARG) {   // verify via table
            const float* sc = sigc + (size_t)arg * MC;
            const float* so = sigo + ((size_t)b * NARG + arg) * NOBJ;
            for (int i = tid; i < PART; i += TS) {
                const int g = base + i;
                const float gg = (g < MC) ? sc[g] : so[g - MC];
                const float nv = fminf(att[i], gg);
                att[i] = nv; hrow[g] = nv;
            }
        } else if (op == 3) {          // verify fallback, arg >= NARG (never hit for this data)
            __syncthreads();
            if (tid < DD) vec[tid] = ct[(size_t)arg * DD + tid];
            __syncthreads();
            const float cn = fmaxf(cnorm[arg], EPSC);
            const float invden = 1.0f / (NSCALE * cn);
            float vv[16];
            {
                const float4 v0 = *(const float4*)&vec[sub * 16 + 0];
                const float4 v1 = *(const float4*)&vec[sub * 16 + 4];
                const float4 v2 = *(const float4*)&vec[sub * 16 + 8];
                const float4 v3 = *(const float4*)&vec[sub * 16 + 12];
                vv[0]=v0.x; vv[1]=v0.y; vv[2]=v0.z; vv[3]=v0.w;
                vv[4]=v1.x; vv[5]=v1.y; vv[6]=v1.z; vv[7]=v1.w;
                vv[8]=v2.x; vv[9]=v2.y; vv[10]=v2.z; vv[11]=v2.w;
                vv[12]=v3.x; vv[13]=v3.y; vv[14]=v3.z; vv[15]=v3.w;
            }
            #pragma unroll
            for (int p = 0; p < 8; p++) SIM_ROW(rg + p * 64, att[_r] = fminf(att[_r], sg));
            if (rg < PART - 512) SIM_ROW(rg + 512, att[_r] = fminf(att[_r], sg));
            __syncthreads();
            for (int i = tid; i < PART; i += TS) hrow[base + i] = att[i];
        } else if (op == 4) {          // choose
            for (int i = tid; i < PART; i += TS) {
                const int g = base + i;
                const float nv = (g < MC) ? ((g == arg) ? 1.0f : 0.0f) : att[i];
                att[i] = nv; hrow[g] = nv;
            }
        } else if (op == 5) {          // exist
            __syncthreads();
            float lm = NINF;
            for (int i = tid; i < PART; i += TS) lm = fmaxf(lm, att[i]);
            #pragma unroll
            for (int off = 32; off; off >>= 1) lm = fmaxf(lm, __shfl_xor(lm, off, 64));
            if (lane == 0) wred[wid] = lm;
            __syncthreads();
            epoch++;
            if (tid == 0) {
                float m = wred[0];
                #pragma unroll
                for (int w = 1; w < 8; w++) m = fmaxf(m, wred[w]);
                AST(&gpb[(size_t)((epoch & 1) * QB + q) * 132 + DD], m);
            }
            QBARRIER();
            if (tid == 0) {
                float* slotR = gpb + (size_t)((epoch & 1) * QB) * 132;
                float m = NINF;
                #pragma unroll
                for (int k = 0; k < QB; k++)
                    m = fmaxf(m, ALD(&slotR[k * 132 + DD]));
                s_sh = m;
            }
            __syncthreads();
            const float s = s_sh;
            const float yes = s * POSC, no = POSC - yes;
            for (int i = tid; i < PART; i += TS) {
                const int g = base + i;
                const float nv = (g == 0) ? yes : ((g == 1) ? no : NEGC);
                att[i] = nv; hrow[g] = nv;
            }
        } else if (op == 6) {          // transfer
            __syncthreads();
            // prefetch rmat rows into regs EARLY; retires under max+gather+exchange
            const float* rm = rt + (size_t)arg * (DD * DD);
            const int half = lane >> 5, dq = (lane & 31) * 4;
            float4 rmr[8];
            #pragma unroll
            for (int j = 0; j < 8; j++) {
                const int d = wid * 16 + half * 8 + j;
                rmr[j] = *(const float4*)(rm + (size_t)d * DD + dq);
            }
            // local max
            float lm = NINF;
            for (int i = tid; i < PART; i += TS) lm = fmaxf(lm, att[i]);
            #pragma unroll
            for (int off = 32; off; off >>= 1) lm = fmaxf(lm, __shfl_xor(lm, off, 64));
            if (lane == 0) wred[wid] = lm;
            // local gather partial over own rows (LDS-resident)
            float ac[16];
            #pragma unroll
            for (int j = 0; j < 16; j++) ac[j] = 0.f;
            #pragma unroll
            for (int p = 0; p < 8; p++) GATH_ROW(rg + p * 64);
            if (rg < PART - 512) GATH_ROW(rg + 512);
            #pragma unroll
            for (int j = 0; j < 16; j++) {
                ac[j] += __shfl_xor(ac[j], 8, 64);
                ac[j] += __shfl_xor(ac[j], 16, 64);
                ac[j] += __shfl_xor(ac[j], 32, 64);
            }
            if (lane < 8) {
                float* dst = &part[wid * DD + lane * 16];
                #pragma unroll
                for (int k = 0; k < 4; k++)
                    *(float4*)(dst + k * 4) = make_float4(ac[k*4], ac[k*4+1], ac[k*4+2], ac[k*4+3]);
            }
            __syncthreads();
            epoch++;
            {
                float* slotW = gpb + (size_t)((epoch & 1) * QB + q) * 132;
                if (tid < DD) {
                    float gsum = 0.f;
                    #pragma unroll
                    for (int w = 0; w < 8; w++) gsum += part[w * DD + tid];
                    AST(&slotW[tid], gsum);
                }
                if (tid == DD) {
                    float m = wred[0];
                    #pragma unroll
                    for (int w = 1; w < 8; w++) m = fmaxf(m, wred[w]);
                    AST(&slotW[DD], m);
                }
            }
            QBARRIER();
            // combine gather partials + global max
            {
                float* slotR = gpb + (size_t)((epoch & 1) * QB) * 132;
                if (tid < DD) {
                    float gsum = 0.f;
                    #pragma unroll
                    for (int k = 0; k < QB; k++)
                        gsum += ALD(&slotR[k * 132 + tid]);
                    gvf[tid] = gsum;
                }
                if (tid == DD) {
                    float m = NINF;
                    #pragma unroll
                    for (int k = 0; k < QB; k++)
                        m = fmaxf(m, ALD(&slotR[k * 132 + DD]));
                    s_sh = m;
                }
            }
            __syncthreads();
            // trans = gvf @ rmat (full, redundant per block, from prefetched regs)
            float qx = 0.f, qy = 0.f, qz = 0.f, qw = 0.f;
            #pragma unroll
            for (int j = 0; j < 8; j++) {
                const int d = wid * 16 + half * 8 + j;
                const float g = gvf[d];
                qx = fmaf(g, rmr[j].x, qx); qy = fmaf(g, rmr[j].y, qy);
                qz = fmaf(g, rmr[j].z, qz); qw = fmaf(g, rmr[j].w, qw);
            }
            qx += __shfl_xor(qx, 32, 64); qy += __shfl_xor(qy, 32, 64);
            qz += __shfl_xor(qz, 32, 64); qw += __shfl_xor(qw, 32, 64);
            if (lane < 32) *(float4*)&part[wid * DD + dq] = make_float4(qx, qy, qz, qw);
            __syncthreads();
            if (tid < DD) {
                float t = 0.f;
                #pragma unroll
                for (int w = 0; w < 8; w++) t += part[w * DD + tid];
                vec[tid] = t;
                float ss = t * t;
                #pragma unroll
                for (int off = 32; off; off >>= 1) ss += __shfl_xor(ss, off, 64);
                if (lane == 0) red2[wid] = ss;
            }
            __syncthreads();
            const float tn = fmaxf(sqrtf(red2[0] + red2[1]), EPSC * NSCALE);
            const float invden = 1.0f / (NSCALE * tn);
            const float s = s_sh;
            float vv[16];
            {
                const float4 v0 = *(const float4*)&vec[sub * 16 + 0];
                const float4 v1 = *(const float4*)&vec[sub * 16 + 4];
                const float4 v2 = *(const float4*)&vec[sub * 16 + 8];
                const float4 v3 = *(const float4*)&vec[sub * 16 + 12];
                vv[0]=v0.x; vv[1]=v0.y; vv[2]=v0.z; vv[3]=v0.w;
                vv[4]=v1.x; vv[5]=v1.y; vv[6]=v1.z; vv[7]=v1.w;
                vv[8]=v2.x; vv[9]=v2.y; vv[10]=v2.z; vv[11]=v2.w;
                vv[12]=v3.x; vv[13]=v3.y; vv[14]=v3.z; vv[15]=v3.w;
            }
            #pragma unroll
            for (int p = 0; p < 8; p++) SIM_ROW(rg + p * 64, att[_r] = sg * s);
            if (rg < PART - 512) SIM_ROW(rg + 512, att[_r] = sg * s);
            __syncthreads();
            for (int i = tid; i < PART; i += TS) hrow[base + i] = att[i];
        }
    }

    // ---- log_softmax over concept rows: single fence-free exchange ----
    __syncthreads();
    const int crows = (base + PART <= MC) ? PART : (MC - base);   // 544,544,544,416
    {
        float lm = NINF;
        for (int i = tid; i < crows; i += TS) lm = fmaxf(lm, att[i]);
        #pragma unroll
        for (int off = 32; off; off >>= 1) lm = fmaxf(lm, __shfl_xor(lm, off, 64));
        if (lane == 0) wred[wid] = lm;
    }
    __syncthreads();
    float mloc = wred[0];
    #pragma unroll
    for (int w = 1; w < 8; w++) mloc = fmaxf(mloc, wred[w]);
    {
        float lse = 0.f;
        for (int i = tid; i < crows; i += TS) lse += expf(att[i] - mloc);
        #pragma unroll
        for (int off = 32; off; off >>= 1) lse += __shfl_xor(lse, off, 64);
        if (lane == 0) red2[wid] = lse;
    }
    __syncthreads();
    epoch++;
    if (tid == 0) {
        float sloc = 0.f;
        #pragma unroll
        for (int w = 0; w < 8; w++) sloc += red2[w];
        float* slotW = gpb + (size_t)((epoch & 1) * QB + q) * 132;
        AST(&slotW[DD], mloc);
        AST(&slotW[DD + 1], sloc);
    }
    QBARRIER();
    if (tid == 0) {
        float* slotR = gpb + (size_t)((epoch & 1) * QB) * 132;
        float mg = NINF;
        float mq[QB], sq[QB];
        #pragma unroll
        for (int k = 0; k < QB; k++) {
            mq[k] = ALD(&slotR[k * 132 + DD]);
            sq[k] = ALD(&slotR[k * 132 + DD + 1]);
            mg = fmaxf(mg, mq[k]);
        }
        float se = 0.f;
        #pragma unroll
        for (int k = 0; k < QB; k++) se += sq[k] * expf(mq[k] - mg);
        s_sh  = mg;
        s_sh2 = logf(se);
    }
    __syncthreads();
    const float mglob = s_sh, ls = s_sh2;
    for (int i = tid; i < crows; i += TS)
        out[(size_t)b * MC + base + i] = att[i] - mglob - ls;
}

extern "C" void kernel_launch(void* const* d_in, const int* in_sizes, int n_in,
                              void* d_out, int out_size, void* d_ws, size_t ws_size,
                              hipStream_t stream) {
    const float* scene = (const float*)d_in[0];
    const int*   prog  = (const int*)d_in[1];
    const float* ct    = (const float*)d_in[2];
    const float* rt    = (const float*)d_in[3];
    const float* W     = (const float*)d_in[4];
    const float* bias  = (const float*)d_in[5];

    float* out  = (float*)d_out;
    float* hist = out + (size_t)BB * MC;

    float* obj   = (float*)d_ws;                               // B*NOBJ*D f32
    float* cnorm = obj + (size_t)BB * NOBJ * DD;               // MC
    float* onorm = cnorm + MC;                                 // B*NOBJ
    float* sigc  = onorm + (size_t)BB * NOBJ;                  // NARG*MC
    float* sigo  = sigc + (size_t)NARG * MC;                   // B*NARG*NOBJ
    float* gpart = sigo + (size_t)BB * NARG * NOBJ;            // B*2*QB*132 f32
    unsigned int* ctrbuf = (unsigned int*)(gpart + (size_t)BB * 2 * QB * 132);  // B*16 u32
    unsigned char* ctf8  = (unsigned char*)(ctrbuf + BB * 16); // MC*DD bytes (normalized fp8)
    unsigned char* objf8 = ctf8 + (size_t)MC * DD;             // B*NOBJ*DD bytes

    gemm_objects<<<dim3(4, BB), 256, 0, stream>>>(scene, W, bias, obj);
    prep_fused<<<dim3(NBN + (MC + BB * NOBJ) / 64), 256, 0, stream>>>(
        ct, obj, cnorm, onorm, ctf8, objf8, ctrbuf, sigc, sigo);
    scan_exec<<<dim3(BB * QB), TS, 0, stream>>>(ct, rt, prog, cnorm, onorm, sigc, sigo,
                                                ctf8, objf8, gpart, ctrbuf, out, hist);
}